// Round 11
// baseline (102.067 us; speedup 1.0000x reference)
//
#include <hip/hip_runtime.h>
#include <hip/hip_bf16.h>

#define NROWS 8192
#define MCOLS 8192
#define DDIM  64

typedef __attribute__((ext_vector_type(8))) short bf16x8;
typedef __attribute__((ext_vector_type(4))) float f32x4;
typedef __attribute__((ext_vector_type(2))) unsigned int u32x2;
typedef __attribute__((ext_vector_type(4))) unsigned int u32x4;

// ws layout (bytes):
//   Xh [512][2][64] x bf16x8 = 1 MiB @ 0        (x-hi fragments, MFMA order)
//   Xl                       = 1 MiB @ 1 MiB
//   Yh                       = 1 MiB @ 2 MiB
//   Yl                       = 1 MiB @ 3 MiB
//   x2 f32[8192] = 32 KiB            @ 4 MiB
//   y2 f32[8192] = 32 KiB            @ 4 MiB + 32 KiB
#define WS_NEED (4ull * 1024 * 1024 + 64 * 1024)

// ---------------- Kernel 1: pack x,y -> scaled bf16 hi/lo fragments + norms ----------------
// frag[rb][kk][lane][e] = v[rb*16 + (lane&15)][kk*32 + (lane>>4)*8 + e]
__global__ __launch_bounds__(256)
void pack_kernel(const float* __restrict__ x, const float* __restrict__ y,
                 const float* __restrict__ log_l, unsigned char* __restrict__ ws)
{
    const int t = threadIdx.x, lane = t & 63, wid = t >> 6;
    const int sub = lane & 15, lg = lane >> 4;
    const int gb  = blockIdx.x;             // 0..255
    const int isY = gb >> 7;                // first 128 blocks: x, rest: y
    const int rb  = ((gb & 127) << 2) | wid;  // 0..511

    const float* __restrict__ src = isY ? y : x;
    bf16x8* __restrict__ Ph = reinterpret_cast<bf16x8*>(ws + (isY ? (2u << 20) : 0u));
    bf16x8* __restrict__ Pl = reinterpret_cast<bf16x8*>(ws + (isY ? (3u << 20) : (1u << 20)));
    float*  __restrict__ nrm = reinterpret_cast<float*>(ws + (4u << 20) + (isY ? (32u << 10) : 0u));

    const int row = rb * 16 + sub;
    float psum = 0.0f;
    #pragma unroll
    for (int kk = 0; kk < 2; ++kk) {
        const int k0 = kk * 32 + lg * 8;
        f32x4 v0 = *reinterpret_cast<const f32x4*>(&src[(size_t)row * DDIM + k0]);
        f32x4 v1 = *reinterpret_cast<const f32x4*>(&src[(size_t)row * DDIM + k0 + 4]);
        f32x4 g0 = *reinterpret_cast<const f32x4*>(&log_l[k0]);
        f32x4 g1 = *reinterpret_cast<const f32x4*>(&log_l[k0 + 4]);
        float s[8];
        #pragma unroll
        for (int j = 0; j < 4; ++j) s[j]     = v0[j] * __expf(-g0[j]);
        #pragma unroll
        for (int j = 0; j < 4; ++j) s[4 + j] = v1[j] * __expf(-g1[j]);
        unsigned int hp[4], lp[4];
        #pragma unroll
        for (int p = 0; p < 4; ++p) {
            float a = s[2 * p], b = s[2 * p + 1];
            psum += a * a + b * b;
            unsigned int ua = __float_as_uint(a), ub = __float_as_uint(b);
            float la = a - __uint_as_float(ua & 0xFFFF0000u);
            float lb = b - __uint_as_float(ub & 0xFFFF0000u);
            hp[p] = (ua >> 16) | (ub & 0xFFFF0000u);
            lp[p] = ((__float_as_uint(la) + 0x8000u) >> 16) |
                    ((__float_as_uint(lb) + 0x8000u) & 0xFFFF0000u);
        }
        const int fi = (rb * 2 + kk) * 64 + lane;
        *reinterpret_cast<u32x4*>(&Ph[fi]) = u32x4{hp[0], hp[1], hp[2], hp[3]};
        *reinterpret_cast<u32x4*>(&Pl[fi]) = u32x4{lp[0], lp[1], lp[2], lp[3]};
    }
    psum += __shfl_xor(psum, 16);
    psum += __shfl_xor(psum, 32);
    if (lg == 0) nrm[row] = psum;
}

// ---------------- Kernel 2: persistent 128-col strips, zero-barrier, 512B store runs ----------------
// Block = 4 waves; wave owns 16 x-rows x 128 y-cols (block tile 64x128). X and Y
// fragments are read DIRECTLY from L2-hot ws (R7: LDS staging of reads is neutral);
// LDS holds only the per-wave transpose tile. After the transpose, each store
// instruction writes 2 rows x 512B contiguous per half-wave (vs 256B before) ->
// longer DRAM runs. Grid 64x16 = 1024 blocks at 4/CU = one clean dispatch round.
// Epilogue folds the RBF algebra: out = exp(c + (lnos - 0.5*x2) + (-0.5*y2)).
__global__ __launch_bounds__(256, 4)
void ard_rbf_main(const unsigned char* __restrict__ ws,
                  const float* __restrict__ log_os, float* __restrict__ out)
{
    __shared__ float tr[4][16][132];   // per-wave 16x128 transpose tile (+4 pad)

    const int t = threadIdx.x, lane = t & 63, wid = t >> 6;
    const int sub = lane & 15, lg = lane >> 4;
    const int h   = lane >> 5;         // half-wave id (0/1)
    const int hc  = lane & 31;         // lane within half-wave
    const int bx = blockIdx.x;         // 0..63  : 128-col y strip
    const int g  = blockIdx.y;         // 0..15  : group of 8 row-tiles (64 rows each)

    const bf16x8* __restrict__ Xh = reinterpret_cast<const bf16x8*>(ws);
    const bf16x8* __restrict__ Xl = reinterpret_cast<const bf16x8*>(ws + (1u << 20));
    const bf16x8* __restrict__ Yh = reinterpret_cast<const bf16x8*>(ws + (2u << 20));
    const bf16x8* __restrict__ Yl = reinterpret_cast<const bf16x8*>(ws + (3u << 20));
    const float*  __restrict__ x2 = reinterpret_cast<const float*>(ws + (4u << 20));
    const float*  __restrict__ y2 = reinterpret_cast<const float*>(ws + (4u << 20) + (32u << 10));

    const float lnos = log_os[0];
    const int cb = bx * 128;
    const f32x4 y2q = *reinterpret_cast<const f32x4*>(&y2[cb + hc * 4]);
    f32x4 ny;                          // -0.5 * y2 for this lane's 4 output cols
    #pragma unroll
    for (int j = 0; j < 4; ++j) ny[j] = -0.5f * y2q[j];

    #pragma unroll
    for (int it = 0; it < 8; ++it) {
        const int bt = g * 8 + it;     // row-tile index, 0..127 (64 rows each)

        // ---- MFMA: wave owns 16 x-rows (frag-row bt*4+wid) x 128 y-cols (8 frag-rows) ----
        f32x4 acc[8] = {};
        #pragma unroll
        for (int kk = 0; kk < 2; ++kk) {
            const int fi = ((bt * 4 + wid) * 2 + kk) * 64 + lane;
            bf16x8 xh = Xh[fi];
            bf16x8 xl = Xl[fi];
            #pragma unroll
            for (int b = 0; b < 8; ++b) {
                const int fj = ((bx * 8 + b) * 2 + kk) * 64 + lane;
                bf16x8 yh = Yh[fj];
                bf16x8 yl = Yl[fj];
                acc[b] = __builtin_amdgcn_mfma_f32_16x16x32_bf16(yh, xh, acc[b], 0, 0, 0);
                acc[b] = __builtin_amdgcn_mfma_f32_16x16x32_bf16(yl, xh, acc[b], 0, 0, 0);
                acc[b] = __builtin_amdgcn_mfma_f32_16x16x32_bf16(yh, xl, acc[b], 0, 0, 0);
            }
        }

        // ---- Per-wave LDS transpose (no barrier; same-wave DS is in-order) ----
        // D[xrow = sub][ycol = b*16 + lg*4 + j] = acc[b][j]
        #pragma unroll
        for (int b = 0; b < 8; ++b)
            *reinterpret_cast<f32x4*>(&tr[wid][sub][b * 16 + lg * 4]) = acc[b];

        // ---- Stores: each instruction writes 2 rows x 512B contiguous per half-wave ----
        const int xb = bt * 64 + wid * 16;
        #pragma unroll
        for (int s = 0; s < 8; ++s) {
            const int rl = s * 2 + h;                    // 0..15 local x-row
            f32x4 c = *reinterpret_cast<const f32x4*>(&tr[wid][rl][hc * 4]);
            const float pre = fmaf(-0.5f, x2[xb + rl], lnos);
            f32x4 v;
            #pragma unroll
            for (int j = 0; j < 4; ++j)
                v[j] = __expf(c[j] + (pre + ny[j]));
            *reinterpret_cast<f32x4*>(out + (size_t)(xb + rl) * MCOLS + cb + hc * 4) = v;
        }
    }
}

// ---------------- Fallback (fused single kernel) if ws is too small ----------------
__global__ __launch_bounds__(512, 4)
void ard_rbf_fallback(const float* __restrict__ x, const float* __restrict__ y,
                      const float* __restrict__ log_l, const float* __restrict__ log_os,
                      float* __restrict__ out)
{
    __shared__ unsigned short Ah[128][DDIM + 8], Al[128][DDIM + 8];
    __shared__ unsigned short Bh[128][DDIM + 8], Bl[128][DDIM + 8];
    __shared__ float x2s[128], y2s[128];
    __shared__ float invl[DDIM];

    const int t = threadIdx.x;
    const int bx = blockIdx.x, by = blockIdx.y;
    const int lane = t & 63, sub = lane & 15, lg = lane >> 4;

    if (t < DDIM) invl[t] = __expf(-log_l[t]);
    __syncthreads();

    #pragma unroll
    for (int ab = 0; ab < 2; ++ab) {
        const float* __restrict__ src = ab ? y : x;
        unsigned short (*Hh)[DDIM + 8] = ab ? Bh : Ah;
        unsigned short (*Hl)[DDIM + 8] = ab ? Bl : Al;
        float* nrm = ab ? y2s : x2s;
        const int tb = (ab ? bx : by) * 128;
        #pragma unroll
        for (int i = 0; i < 4; ++i) {
            const int f = i * 512 + t;
            const int row = f >> 4;
            const int c4 = (f & 15) * 4;
            f32x4 v = *reinterpret_cast<const f32x4*>(&src[(size_t)(tb + row) * DDIM + c4]);
            f32x4 il = *reinterpret_cast<const f32x4*>(&invl[c4]);
            float s0 = v[0] * il[0], s1 = v[1] * il[1], s2 = v[2] * il[2], s3 = v[3] * il[3];
            float psum = s0 * s0 + s1 * s1 + s2 * s2 + s3 * s3;
            unsigned int u0 = __float_as_uint(s0), u1 = __float_as_uint(s1);
            unsigned int u2 = __float_as_uint(s2), u3 = __float_as_uint(s3);
            float l0 = s0 - __uint_as_float(u0 & 0xFFFF0000u);
            float l1 = s1 - __uint_as_float(u1 & 0xFFFF0000u);
            float l2 = s2 - __uint_as_float(u2 & 0xFFFF0000u);
            float l3 = s3 - __uint_as_float(u3 & 0xFFFF0000u);
            unsigned int hp0 = (u0 >> 16) | (u1 & 0xFFFF0000u);
            unsigned int hp1 = (u2 >> 16) | (u3 & 0xFFFF0000u);
            unsigned int lp0 = ((__float_as_uint(l0) + 0x8000u) >> 16) | ((__float_as_uint(l1) + 0x8000u) & 0xFFFF0000u);
            unsigned int lp1 = ((__float_as_uint(l2) + 0x8000u) >> 16) | ((__float_as_uint(l3) + 0x8000u) & 0xFFFF0000u);
            psum += __shfl_xor(psum, 1);
            psum += __shfl_xor(psum, 2);
            psum += __shfl_xor(psum, 4);
            psum += __shfl_xor(psum, 8);
            *reinterpret_cast<u32x2*>(&Hh[row][c4]) = u32x2{hp0, hp1};
            *reinterpret_cast<u32x2*>(&Hl[row][c4]) = u32x2{lp0, lp1};
            if (sub == 0) nrm[row] = psum;
        }
    }
    __syncthreads();

    const int wid = t >> 6;
    const int wr = wid >> 2, wc = wid & 3;
    f32x4 acc[4][2] = {};
    #pragma unroll
    for (int kk = 0; kk < 2; ++kk) {
        const int kb = kk * 32 + lg * 8;
        bf16x8 ah[4], al[4];
        #pragma unroll
        for (int m = 0; m < 4; ++m) {
            const int r = wr * 64 + m * 16 + sub;
            ah[m] = *reinterpret_cast<const bf16x8*>(&Ah[r][kb]);
            al[m] = *reinterpret_cast<const bf16x8*>(&Al[r][kb]);
        }
        #pragma unroll
        for (int n = 0; n < 2; ++n) {
            const int c = wc * 32 + n * 16 + sub;
            bf16x8 bh = *reinterpret_cast<const bf16x8*>(&Bh[c][kb]);
            bf16x8 bl = *reinterpret_cast<const bf16x8*>(&Bl[c][kb]);
            #pragma unroll
            for (int m = 0; m < 4; ++m) {
                acc[m][n] = __builtin_amdgcn_mfma_f32_16x16x32_bf16(ah[m], bh, acc[m][n], 0, 0, 0);
                acc[m][n] = __builtin_amdgcn_mfma_f32_16x16x32_bf16(al[m], bh, acc[m][n], 0, 0, 0);
                acc[m][n] = __builtin_amdgcn_mfma_f32_16x16x32_bf16(ah[m], bl, acc[m][n], 0, 0, 0);
            }
        }
    }
    const float lnos = log_os[0];
    #pragma unroll
    for (int m = 0; m < 4; ++m) {
        const int rl0 = wr * 64 + m * 16 + lg * 4;
        #pragma unroll
        for (int n = 0; n < 2; ++n) {
            const int cl = wc * 32 + n * 16 + sub;
            const float yy2 = y2s[cl];
            const size_t g0 = (size_t)(by * 128 + rl0) * MCOLS + (size_t)(bx * 128 + cl);
            #pragma unroll
            for (int j = 0; j < 4; ++j) {
                float sq = fmaxf(x2s[rl0 + j] + yy2 - 2.0f * acc[m][n][j], 0.0f);
                out[g0 + (size_t)j * MCOLS] = __expf(fmaf(-0.5f, sq, lnos));
            }
        }
    }
}

extern "C" void kernel_launch(void* const* d_in, const int* in_sizes, int n_in,
                              void* d_out, int out_size, void* d_ws, size_t ws_size,
                              hipStream_t stream) {
    const float* x      = (const float*)d_in[0];
    const float* y      = (const float*)d_in[1];
    const float* log_l  = (const float*)d_in[2];
    const float* log_os = (const float*)d_in[3];
    float* out = (float*)d_out;

    if (ws_size >= WS_NEED) {
        pack_kernel<<<256, 256, 0, stream>>>(x, y, log_l, (unsigned char*)d_ws);
        ard_rbf_main<<<dim3(64, 16), 256, 0, stream>>>((const unsigned char*)d_ws, log_os, out);
    } else {
        ard_rbf_fallback<<<dim3(64, 64), 512, 0, stream>>>(x, y, log_l, log_os, out);
    }
}

// Round 13
// 54.293 us; speedup vs baseline: 1.8799x; 1.8799x over previous
//
#include <hip/hip_runtime.h>
#include <hip/hip_bf16.h>

#define NROWS 8192
#define MCOLS 8192
#define DDIM  64

typedef __attribute__((ext_vector_type(8))) short bf16x8;
typedef __attribute__((ext_vector_type(4))) float f32x4;
typedef __attribute__((ext_vector_type(2))) unsigned int u32x2;
typedef __attribute__((ext_vector_type(4))) unsigned int u32x4;

// ws layout (bytes):
//   Xh [512][2][64] x bf16x8 = 1 MiB @ 0        (x-hi fragments, MFMA order)
//   Xl                       = 1 MiB @ 1 MiB
//   Yh                       = 1 MiB @ 2 MiB
//   Yl                       = 1 MiB @ 3 MiB
//   x2 f32[8192] = 32 KiB            @ 4 MiB
//   y2 f32[8192] = 32 KiB            @ 4 MiB + 32 KiB
#define WS_NEED (4ull * 1024 * 1024 + 64 * 1024)

__device__ __forceinline__ void gld_lds16(const unsigned char* g, unsigned char* l) {
    __builtin_amdgcn_global_load_lds(
        (const __attribute__((address_space(1))) void*)g,
        (__attribute__((address_space(3))) void*)l, 16, 0, 0);
}

// ---------------- Kernel 1: pack x,y -> scaled bf16 hi/lo fragments + norms ----------------
// frag[rb][kk][lane][e] = v[rb*16 + (lane&15)][kk*32 + (lane>>4)*8 + e]
__global__ __launch_bounds__(256)
void pack_kernel(const float* __restrict__ x, const float* __restrict__ y,
                 const float* __restrict__ log_l, unsigned char* __restrict__ ws)
{
    const int t = threadIdx.x, lane = t & 63, wid = t >> 6;
    const int sub = lane & 15, lg = lane >> 4;
    const int gb  = blockIdx.x;             // 0..255
    const int isY = gb >> 7;                // first 128 blocks: x, rest: y
    const int rb  = ((gb & 127) << 2) | wid;  // 0..511

    const float* __restrict__ src = isY ? y : x;
    bf16x8* __restrict__ Ph = reinterpret_cast<bf16x8*>(ws + (isY ? (2u << 20) : 0u));
    bf16x8* __restrict__ Pl = reinterpret_cast<bf16x8*>(ws + (isY ? (3u << 20) : (1u << 20)));
    float*  __restrict__ nrm = reinterpret_cast<float*>(ws + (4u << 20) + (isY ? (32u << 10) : 0u));

    const int row = rb * 16 + sub;
    float psum = 0.0f;
    #pragma unroll
    for (int kk = 0; kk < 2; ++kk) {
        const int k0 = kk * 32 + lg * 8;
        f32x4 v0 = *reinterpret_cast<const f32x4*>(&src[(size_t)row * DDIM + k0]);
        f32x4 v1 = *reinterpret_cast<const f32x4*>(&src[(size_t)row * DDIM + k0 + 4]);
        f32x4 g0 = *reinterpret_cast<const f32x4*>(&log_l[k0]);
        f32x4 g1 = *reinterpret_cast<const f32x4*>(&log_l[k0 + 4]);
        float s[8];
        #pragma unroll
        for (int j = 0; j < 4; ++j) s[j]     = v0[j] * __expf(-g0[j]);
        #pragma unroll
        for (int j = 0; j < 4; ++j) s[4 + j] = v1[j] * __expf(-g1[j]);
        unsigned int hp[4], lp[4];
        #pragma unroll
        for (int p = 0; p < 4; ++p) {
            float a = s[2 * p], b = s[2 * p + 1];
            psum += a * a + b * b;
            unsigned int ua = __float_as_uint(a), ub = __float_as_uint(b);
            float la = a - __uint_as_float(ua & 0xFFFF0000u);
            float lb = b - __uint_as_float(ub & 0xFFFF0000u);
            hp[p] = (ua >> 16) | (ub & 0xFFFF0000u);
            lp[p] = ((__float_as_uint(la) + 0x8000u) >> 16) |
                    ((__float_as_uint(lb) + 0x8000u) & 0xFFFF0000u);
        }
        const int fi = (rb * 2 + kk) * 64 + lane;
        *reinterpret_cast<u32x4*>(&Ph[fi]) = u32x4{hp[0], hp[1], hp[2], hp[3]};
        *reinterpret_cast<u32x4*>(&Pl[fi]) = u32x4{lp[0], lp[1], lp[2], lp[3]};
    }
    psum += __shfl_xor(psum, 16);
    psum += __shfl_xor(psum, 32);
    if (lg == 0) nrm[row] = psum;
}

// ---------------- Kernel 2: persistent column-strip blocks, barrier-free inner loop ----------------
// Block owns a 64-col y strip; stages Y frags into LDS ONCE (one barrier), then loops
// over 8 row-tiles (128 x-rows each) with NO barriers. Grid = 128x8 = 1024 blocks at
// 4 blocks/CU = exactly ONE full-GPU dispatch round.
// Epilogue folds the RBF algebra: out = exp(c + (lnos - 0.5*x2) + (-0.5*y2)).
// Transpose writes are UNPREDICATED full-tile (predicated half-tile variant raced, R11).
__global__ __launch_bounds__(256, 4)
void ard_rbf_main(const unsigned char* __restrict__ ws,
                  const float* __restrict__ log_os, float* __restrict__ out)
{
    __shared__ __align__(1024) unsigned char smemY[16 * 1024];
    __shared__ float tr[4][16][68];    // per-wave transpose tile

    const int t = threadIdx.x, lane = t & 63, wid = t >> 6;
    const int sub = lane & 15, lg = lane >> 4;
    const int bx = blockIdx.x;         // 0..127 : 64-col y strip
    const int g  = blockIdx.y;         // 0..7   : group of 8 row-tiles

    const bf16x8* __restrict__ Xh = reinterpret_cast<const bf16x8*>(ws);
    const bf16x8* __restrict__ Xl = reinterpret_cast<const bf16x8*>(ws + (1u << 20));
    const float*  __restrict__ x2 = reinterpret_cast<const float*>(ws + (4u << 20));
    const float*  __restrict__ y2 = reinterpret_cast<const float*>(ws + (4u << 20) + (32u << 10));

    // ---- Stage Y frags (16 chunks x 1KB) into LDS once; chunk c = fry*4 + kk*2 + hl ----
    #pragma unroll
    for (int i = 0; i < 4; ++i) {
        const int c = wid * 4 + i;
        const int fry = c >> 2, kk = (c >> 1) & 1, hl = c & 1;
        const size_t goff = (2u << 20) + ((size_t)hl << 20)
                          + ((size_t)((((bx * 4 + fry) * 2 + kk) * 64 + lane)) << 4);
        gld_lds16(ws + goff, smemY + c * 1024);
    }
    __syncthreads();   // only barrier in the kernel

    const float lnos = log_os[0];
    const int ybase = bx * 64;
    const f32x4 y2q = *reinterpret_cast<const f32x4*>(&y2[ybase + sub * 4]);
    f32x4 ny;                          // -0.5 * y2, per-thread constant
    #pragma unroll
    for (int j = 0; j < 4; ++j) ny[j] = -0.5f * y2q[j];

    #pragma unroll
    for (int it = 0; it < 8; ++it) {
        const int by = g * 8 + it;

        // ---- MFMA: wave owns 32 x-rows x 64 y-cols; X direct from ws, Y from LDS ----
        f32x4 acc[2][4] = {};
        #pragma unroll
        for (int kk = 0; kk < 2; ++kk) {
            bf16x8 xh[2], xl[2], yh[4], yl[4];
            #pragma unroll
            for (int a = 0; a < 2; ++a) {
                const int fi = ((by * 8 + wid * 2 + a) * 2 + kk) * 64 + lane;
                xh[a] = Xh[fi];
                xl[a] = Xl[fi];
            }
            #pragma unroll
            for (int b = 0; b < 4; ++b) {
                yh[b] = *reinterpret_cast<const bf16x8*>(smemY + (b * 4 + kk * 2 + 0) * 1024 + lane * 16);
                yl[b] = *reinterpret_cast<const bf16x8*>(smemY + (b * 4 + kk * 2 + 1) * 1024 + lane * 16);
            }
            #pragma unroll
            for (int a = 0; a < 2; ++a)
                #pragma unroll
                for (int b = 0; b < 4; ++b) {
                    acc[a][b] = __builtin_amdgcn_mfma_f32_16x16x32_bf16(yh[b], xh[a], acc[a][b], 0, 0, 0);
                    acc[a][b] = __builtin_amdgcn_mfma_f32_16x16x32_bf16(yl[b], xh[a], acc[a][b], 0, 0, 0);
                    acc[a][b] = __builtin_amdgcn_mfma_f32_16x16x32_bf16(yh[b], xl[a], acc[a][b], 0, 0, 0);
                }
        }

        // ---- Epilogue: 2-pass per-wave transpose (no barrier; same-wave DS in-order) ----
        // D[xrow = a*16 + sub][ycol = b*16 + lg*4 + j] = acc[a][b][j]
        #pragma unroll
        for (int a = 0; a < 2; ++a) {
            #pragma unroll
            for (int b = 0; b < 4; ++b)
                *reinterpret_cast<f32x4*>(&tr[wid][sub][b * 16 + lg * 4]) = acc[a][b];
            const int xb = by * 128 + wid * 32 + a * 16;
            #pragma unroll
            for (int r = 0; r < 4; ++r) {
                const int rl = r * 4 + lg;
                f32x4 c = *reinterpret_cast<const f32x4*>(&tr[wid][rl][sub * 4]);
                const float pre = fmaf(-0.5f, x2[xb + rl], lnos);   // per-row
                f32x4 v;
                #pragma unroll
                for (int j = 0; j < 4; ++j)
                    v[j] = __expf(c[j] + (pre + ny[j]));
                *reinterpret_cast<f32x4*>(out + (size_t)(xb + rl) * MCOLS + ybase + sub * 4) = v;
            }
        }
    }
}

// ---------------- Fallback (fused single kernel) if ws is too small ----------------
__global__ __launch_bounds__(512, 4)
void ard_rbf_fallback(const float* __restrict__ x, const float* __restrict__ y,
                      const float* __restrict__ log_l, const float* __restrict__ log_os,
                      float* __restrict__ out)
{
    __shared__ unsigned short Ah[128][DDIM + 8], Al[128][DDIM + 8];
    __shared__ unsigned short Bh[128][DDIM + 8], Bl[128][DDIM + 8];
    __shared__ float x2s[128], y2s[128];
    __shared__ float invl[DDIM];

    const int t = threadIdx.x;
    const int bx = blockIdx.x, by = blockIdx.y;
    const int lane = t & 63, sub = lane & 15, lg = lane >> 4;

    if (t < DDIM) invl[t] = __expf(-log_l[t]);
    __syncthreads();

    #pragma unroll
    for (int ab = 0; ab < 2; ++ab) {
        const float* __restrict__ src = ab ? y : x;
        unsigned short (*Hh)[DDIM + 8] = ab ? Bh : Ah;
        unsigned short (*Hl)[DDIM + 8] = ab ? Bl : Al;
        float* nrm = ab ? y2s : x2s;
        const int tb = (ab ? bx : by) * 128;
        #pragma unroll
        for (int i = 0; i < 4; ++i) {
            const int f = i * 512 + t;
            const int row = f >> 4;
            const int c4 = (f & 15) * 4;
            f32x4 v = *reinterpret_cast<const f32x4*>(&src[(size_t)(tb + row) * DDIM + c4]);
            f32x4 il = *reinterpret_cast<const f32x4*>(&invl[c4]);
            float s0 = v[0] * il[0], s1 = v[1] * il[1], s2 = v[2] * il[2], s3 = v[3] * il[3];
            float psum = s0 * s0 + s1 * s1 + s2 * s2 + s3 * s3;
            unsigned int u0 = __float_as_uint(s0), u1 = __float_as_uint(s1);
            unsigned int u2 = __float_as_uint(s2), u3 = __float_as_uint(s3);
            float l0 = s0 - __uint_as_float(u0 & 0xFFFF0000u);
            float l1 = s1 - __uint_as_float(u1 & 0xFFFF0000u);
            float l2 = s2 - __uint_as_float(u2 & 0xFFFF0000u);
            float l3 = s3 - __uint_as_float(u3 & 0xFFFF0000u);
            unsigned int hp0 = (u0 >> 16) | (u1 & 0xFFFF0000u);
            unsigned int hp1 = (u2 >> 16) | (u3 & 0xFFFF0000u);
            unsigned int lp0 = ((__float_as_uint(l0) + 0x8000u) >> 16) | ((__float_as_uint(l1) + 0x8000u) & 0xFFFF0000u);
            unsigned int lp1 = ((__float_as_uint(l2) + 0x8000u) >> 16) | ((__float_as_uint(l3) + 0x8000u) & 0xFFFF0000u);
            psum += __shfl_xor(psum, 1);
            psum += __shfl_xor(psum, 2);
            psum += __shfl_xor(psum, 4);
            psum += __shfl_xor(psum, 8);
            *reinterpret_cast<u32x2*>(&Hh[row][c4]) = u32x2{hp0, hp1};
            *reinterpret_cast<u32x2*>(&Hl[row][c4]) = u32x2{lp0, lp1};
            if (sub == 0) nrm[row] = psum;
        }
    }
    __syncthreads();

    const int wid = t >> 6;
    const int wr = wid >> 2, wc = wid & 3;
    f32x4 acc[4][2] = {};
    #pragma unroll
    for (int kk = 0; kk < 2; ++kk) {
        const int kb = kk * 32 + lg * 8;
        bf16x8 ah[4], al[4];
        #pragma unroll
        for (int m = 0; m < 4; ++m) {
            const int r = wr * 64 + m * 16 + sub;
            ah[m] = *reinterpret_cast<const bf16x8*>(&Ah[r][kb]);
            al[m] = *reinterpret_cast<const bf16x8*>(&Al[r][kb]);
        }
        #pragma unroll
        for (int n = 0; n < 2; ++n) {
            const int c = wc * 32 + n * 16 + sub;
            bf16x8 bh = *reinterpret_cast<const bf16x8*>(&Bh[c][kb]);
            bf16x8 bl = *reinterpret_cast<const bf16x8*>(&Bl[c][kb]);
            #pragma unroll
            for (int m = 0; m < 4; ++m) {
                acc[m][n] = __builtin_amdgcn_mfma_f32_16x16x32_bf16(ah[m], bh, acc[m][n], 0, 0, 0);
                acc[m][n] = __builtin_amdgcn_mfma_f32_16x16x32_bf16(al[m], bh, acc[m][n], 0, 0, 0);
                acc[m][n] = __builtin_amdgcn_mfma_f32_16x16x32_bf16(ah[m], bl, acc[m][n], 0, 0, 0);
            }
        }
    }
    const float lnos = log_os[0];
    #pragma unroll
    for (int m = 0; m < 4; ++m) {
        const int rl0 = wr * 64 + m * 16 + lg * 4;
        #pragma unroll
        for (int n = 0; n < 2; ++n) {
            const int cl = wc * 32 + n * 16 + sub;
            const float yy2 = y2s[cl];
            const size_t g0 = (size_t)(by * 128 + rl0) * MCOLS + (size_t)(bx * 128 + cl);
            #pragma unroll
            for (int j = 0; j < 4; ++j) {
                float sq = fmaxf(x2s[rl0 + j] + yy2 - 2.0f * acc[m][n][j], 0.0f);
                out[g0 + (size_t)j * MCOLS] = __expf(fmaf(-0.5f, sq, lnos));
            }
        }
    }
}

extern "C" void kernel_launch(void* const* d_in, const int* in_sizes, int n_in,
                              void* d_out, int out_size, void* d_ws, size_t ws_size,
                              hipStream_t stream) {
    const float* x      = (const float*)d_in[0];
    const float* y      = (const float*)d_in[1];
    const float* log_l  = (const float*)d_in[2];
    const float* log_os = (const float*)d_in[3];
    float* out = (float*)d_out;

    if (ws_size >= WS_NEED) {
        pack_kernel<<<256, 256, 0, stream>>>(x, y, log_l, (unsigned char*)d_ws);
        ard_rbf_main<<<dim3(128, 8), 256, 0, stream>>>((const unsigned char*)d_ws, log_os, out);
    } else {
        ard_rbf_fallback<<<dim3(64, 64), 512, 0, stream>>>(x, y, log_l, log_os, out);
    }
}